// Round 10
// baseline (49.210 us; speedup 1.0000x reference)
//
#include <hip/hip_runtime.h>

// Path signature, depth 4, D=8. Output layout (matches JAX flatten):
//   s1[8] | s2[64] (i*8+j) | s3[512] (i*64+j*8+k) | s4[4096] (i*512+j*64+k*8+l)
//
// TWO kernels, 2-level tree (each inter-kernel dependency edge costs ~7us in
// dispatch+coherence; 3-level tree floor was ~28us; in-kernel flag handoffs
// are WORSE than a kernel boundary — measured rounds 3/6/9):
//   k1: 64 blocks, each computes the signature of its 128-increment chunk
//       (state fully thread-private in registers, barrier-free scan).
//   k2: 1 block folds all 64 partials serially (Chen product): lower levels
//       of sigs 1..63 staged into 149KB LDS (4 register-batches, 2-deep
//       pipelined); B.s4 own-slice via 2-deep register double-buffer.
// N=64 balances k1 scan (len*~80cy) vs k2 folds (N*~190cy): optimum ~67.
#define SIGLEN 4680
#define S1OFF 0
#define S2OFF 8
#define S3OFF 72
#define S4OFF 584
#define NCHUNK 64
#define MAXLEN 128
#define LROW 592   // LDS floats per staged sig (584 + 8 pad)
#define NFOLD 63   // sigs folded into sig 0 by k2
#define NCH4 (NFOLD * 146)  // float4 chunks staged = 9198

struct SigRegs { float s4[16]; float a1, a2, a30, a31; };

// s3 chunk swizzle: float4 chunk c (0..127) lives at float-offset
// S3OFF + 4*(c ^ ((c>>4)&7)). Involution, bijective, 16B-aligned. Makes the
// 16*(t&31)-pattern b128 reads 4-way instead of 16-way conflicted.
__device__ __forceinline__ int s3off(int c) {
  return S3OFF + 4 * (c ^ ((c >> 4) & 7));
}

__device__ __forceinline__ void load_sig(SigRegs& A, const float* __restrict__ B,
                                         int i_idx, int t) {
  const float4* p4 = (const float4*)(B + S4OFF + 16 * t);
#pragma unroll
  for (int r = 0; r < 4; ++r) {
    const float4 v = p4[r];
    A.s4[4 * r] = v.x; A.s4[4 * r + 1] = v.y; A.s4[4 * r + 2] = v.z; A.s4[4 * r + 3] = v.w;
  }
  A.a1 = B[S1OFF + i_idx];
  A.a2 = B[S2OFF + (t >> 2)];
  const float2 a3i = *(const float2*)(B + S3OFF + 2 * t);
  A.a30 = a3i.x; A.a31 = a3i.y;
}

__device__ __forceinline__ void store_sig(const SigRegs& A, float* __restrict__ o,
                                          int i_idx, int t) {
  if ((t & 31) == 0) o[S1OFF + i_idx] = A.a1;
  if ((t & 3) == 0) o[S2OFF + (t >> 2)] = A.a2;
  *(float2*)(o + S3OFF + 2 * t) = make_float2(A.a30, A.a31);
  float4* o4 = (float4*)(o + S4OFF + 16 * t);
#pragma unroll
  for (int r = 0; r < 4; ++r)
    o4[r] = make_float4(A.s4[4 * r], A.s4[4 * r + 1], A.s4[4 * r + 2], A.s4[4 * r + 3]);
}

// Chen left-fold A <- A*B; B lower levels from LDS row R, B.s4 own-slice from
// registers q4. Math identical to the verified round-2 kernel:
//   c4 = a4 + b4 + a1(x)b3 + a2(x)b2 + a3(x)b1
//   c3 = a3 + b3 + a1(x)b2 + a2(x)b1 ; c2 = a2 + b2 + a1(x)b1 ; c1 = a1 + b1
__device__ __forceinline__ void fold_lds(SigRegs& A, const float* __restrict__ R,
                                         const float4* __restrict__ q4,
                                         int i_idx, int j_idx, int k0, int t) {
  const float4 b1lo = *(const float4*)(R + S1OFF);
  const float4 b1hi = *(const float4*)(R + S1OFF + 4);
  const float b1i = R[S1OFF + i_idx];
  const float b1j = R[S1OFF + j_idx];
  const float2 b1k = *(const float2*)(R + S1OFF + k0);
  const float b2own = R[S2OFF + (t >> 2)];
  const float2 b2p = *(const float2*)(R + S2OFF + ((2 * t) & 63));
  const float2 b3p = *(const float2*)(R + s3off(t >> 1) + 2 * (t & 1));
  const float4* q2 = (const float4*)(R + S2OFF + 16 * (t & 3));
#pragma unroll
  for (int r = 0; r < 4; ++r) {
    const float4 v2 = q2[r];
    const float4 v3 = *(const float4*)(R + s3off(4 * (t & 31) + r));
    const float4 v4 = q4[r];
    const float a3v = (r < 2) ? A.a30 : A.a31;   // e<8 -> a30
    const float4 bb = (r & 1) ? b1hi : b1lo;     // b1v[(4r+c)&7]
    A.s4[4 * r + 0] += v4.x + A.a1 * v3.x + A.a2 * v2.x + a3v * bb.x;
    A.s4[4 * r + 1] += v4.y + A.a1 * v3.y + A.a2 * v2.y + a3v * bb.y;
    A.s4[4 * r + 2] += v4.z + A.a1 * v3.z + A.a2 * v2.z + a3v * bb.z;
    A.s4[4 * r + 3] += v4.w + A.a1 * v3.w + A.a2 * v2.w + a3v * bb.w;
  }
  A.a30 += b3p.x + A.a1 * b2p.x + A.a2 * b1k.x;
  A.a31 += b3p.y + A.a1 * b2p.y + A.a2 * b1k.y;
  A.a2 += b2own + A.a1 * b1j;
  A.a1 += b1i;
}

__device__ __forceinline__ void loadq4(float4* dst, const float* __restrict__ gbase,
                                       int m, int t) {
  const float4* g = (const float4*)(gbase + (long)m * SIGLEN + S4OFF + 16 * t);
#pragma unroll
  for (int r = 0; r < 4; ++r) dst[r] = g[r];
}

// ------------------------- kernel 1: chunk signatures -------------------------
__global__ __launch_bounds__(256, 1) void sig_chunk(const float* __restrict__ path,
                                                    float* __restrict__ partials,
                                                    int nInc) {
  __shared__ float4 pl[(MAXLEN + 1) * 2];
  __shared__ float4 dv[MAXLEN * 2];
  const int t = threadIdx.x;
  const int c = blockIdx.x;
  const int i_idx = t >> 5;
  const int j_idx = (t >> 2) & 7;
  const int k0 = 2 * (t & 3);

  const long start = ((long)c * nInc) / NCHUNK;
  const long end = ((long)(c + 1) * nInc) / NCHUNK;
  const int len = (int)(end - start);

  const float4* gp = (const float4*)(path + start * 8);
  for (int idx = t; idx < (len + 1) * 2; idx += 256) pl[idx] = gp[idx];
  __syncthreads();
  for (int idx = t; idx < len * 2; idx += 256) {
    float4 a = pl[idx + 2], b = pl[idx];
    dv[idx] = make_float4(a.x - b.x, a.y - b.y, a.z - b.z, a.w - b.w);
  }
  __syncthreads();
  const float* dvf = (const float*)dv;

  SigRegs A;
#pragma unroll
  for (int e = 0; e < 16; ++e) A.s4[e] = 0.f;
  A.a1 = 0.f; A.a2 = 0.f; A.a30 = 0.f; A.a31 = 0.f;

  for (int it = 0; it < len; ++it) {
    const float4 d0 = dv[it * 2], d1 = dv[it * 2 + 1];
    const float dxl[8] = {d0.x, d0.y, d0.z, d0.w, d1.x, d1.y, d1.z, d1.w};
    const float dxi = dvf[it * 8 + i_idx];
    const float dxj = dvf[it * 8 + j_idx];
    const float2 dkk = *(const float2*)(dvf + it * 8 + k0);

    const float inner = 0.5f * A.a2 + dxj * ((1.f / 6.f) * A.a1 + (1.f / 24.f) * dxi);
    const float c0 = A.a30 + dkk.x * inner;
    const float c1 = A.a31 + dkk.y * inner;
#pragma unroll
    for (int l = 0; l < 8; ++l) A.s4[l] += c0 * dxl[l];
#pragma unroll
    for (int l = 0; l < 8; ++l) A.s4[8 + l] += c1 * dxl[l];
    const float common3 = A.a2 + dxj * (0.5f * A.a1 + (1.f / 6.f) * dxi);
    A.a30 += common3 * dkk.x;
    A.a31 += common3 * dkk.y;
    A.a2 += dxj * (A.a1 + 0.5f * dxi);
    A.a1 += dxi;
  }

  store_sig(A, partials + (long)c * SIGLEN, i_idx, t);
}

// ------------- kernel 2: single block folds all 64 partials -> out -------------
// Staging: lower levels of sigs 1..63 (9198 float4 chunks) into LDS rows
// 0..62. 4 register batches of 9 chunks/thread, software-pipelined 2-deep
// (issue k+1's loads before writing k) -> ~1 latency exposure, 72 VGPR peak.
__global__ __launch_bounds__(256, 1) void sig_fold_all(const float* __restrict__ partials,
                                                       float* __restrict__ out) {
  __shared__ float lsig[NFOLD * LROW];  // 149184 B
  const int t = threadIdx.x;
  const int i_idx = t >> 5;
  const int j_idx = (t >> 2) & 7;
  const int k0 = 2 * (t & 3);
  const float* gb = partials + SIGLEN;  // sig 1 (rows 0..62 = sigs 1..63)

#define LOADB(buf, k)                                                         \
  _Pragma("unroll") for (int s = 0; s < 9; ++s) {                             \
    const int g = t + 256 * (9 * (k) + s);                                    \
    const int gc = (g < NCH4) ? g : (NCH4 - 1);                               \
    const int sig = gc / 146;                                                 \
    const int r = gc - sig * 146;                                             \
    buf[s] = *(const float4*)(gb + (long)sig * SIGLEN + 4 * r);               \
  }
#define WRITEB(buf, k)                                                        \
  _Pragma("unroll") for (int s = 0; s < 9; ++s) {                             \
    const int g = t + 256 * (9 * (k) + s);                                    \
    if (g < NCH4) {                                                           \
      const int sig = g / 146;                                                \
      const int r = g - sig * 146;                                            \
      const int off = (r < 18) ? 4 * r : s3off(r - 18);                       \
      *(float4*)(lsig + sig * LROW + off) = buf[s];                           \
    }                                                                         \
  }

  float4 va[9], vb[9];
  LOADB(va, 0);
  LOADB(vb, 1);

  SigRegs A;
  load_sig(A, partials, i_idx, t);  // A = sig 0
  float4 qA[4], qB[4];
  loadq4(qA, gb, 0, t);  // sig 1's s4 slice
  loadq4(qB, gb, 1, t);

  WRITEB(va, 0);
  LOADB(va, 2);
  WRITEB(vb, 1);
  LOADB(vb, 3);
  WRITEB(va, 2);
  WRITEB(vb, 3);
#undef LOADB
#undef WRITEB
  __syncthreads();  // LDS staging complete

  // 63 folds: runtime loop, 2-wide software pipeline, named double-buffer
  // (live-set control; deeper rings / full unroll spilled in rounds 4-5).
#pragma unroll 1
  for (int m = 0; m + 2 < NFOLD; m += 2) {  // m = 0,2,...,60 (62 folds)
    fold_lds(A, lsig + m * LROW, qA, i_idx, j_idx, k0, t);
    loadq4(qA, gb, m + 2, t);
    fold_lds(A, lsig + (m + 1) * LROW, qB, i_idx, j_idx, k0, t);
    if (m + 3 < NFOLD) loadq4(qB, gb, m + 3, t);
  }
  fold_lds(A, lsig + (NFOLD - 1) * LROW, qA, i_idx, j_idx, k0, t);  // fold 63
  store_sig(A, out, i_idx, t);
}

extern "C" void kernel_launch(void* const* d_in, const int* in_sizes, int n_in,
                              void* d_out, int out_size, void* d_ws, size_t ws_size,
                              hipStream_t stream) {
  const float* path = (const float*)d_in[0];
  float* out = (float*)d_out;
  const int L = in_sizes[0] / 8;
  const int nInc = L - 1;

  float* partials = (float*)d_ws;  // NCHUNK * SIGLEN floats

  sig_chunk<<<NCHUNK, 256, 0, stream>>>(path, partials, nInc);
  sig_fold_all<<<1, 256, 0, stream>>>(partials, out);
}

// Round 11
// 28.360 us; speedup vs baseline: 1.7352x; 1.7352x over previous
//
#include <hip/hip_runtime.h>

// Path signature, depth 4, D=8. Output layout (matches JAX flatten):
//   s1[8] | s2[64] (i*8+j) | s3[512] (i*64+j*8+k) | s4[4096] (i*512+j*64+k*8+l)
//
// Three kernels, 8x8 tree (cost model from rounds 7-10: serial Chen fold
// ~0.6us each, kernel boundary ~2.5us, in-kernel handoff ~9us => minimize
// critical-path folds: 64 chunks -> 8 blocks x 7 folds -> 1 block x 7 folds
// = 14 serial folds vs 30 for the 16x16 tree; k1 grows 32->128 iters (+1.6us).
//   k1: 64 blocks, each computes the signature of its 128-increment chunk
//       (state fully thread-private in registers, barrier-free scan)
//   k2: 8 blocks, each folds 8 chunk sigs (Chen product, LDS-staged B)
//   k3: 1 block, folds the 8 group sigs into d_out
// Fold engine (validated rounds 6-8): B lower levels (s1..s3) staged in LDS
// once per fold phase (one static batch); B.s4 own-slice via 2-deep register
// double-buffer. Fold loop NOT unrolled (live-set control; 4-deep ring + full
// unroll spilled in round 4: VGPR=256, +10MB scratch writes, 3x slower).
#define SIGLEN 4680
#define S1OFF 0
#define S2OFF 8
#define S3OFF 72
#define S4OFF 584
#define NCHUNK 64
#define NG 8
#define MAXLEN 128
#define LROW 592  // LDS floats per staged sig (584 + 8 pad)

struct SigRegs { float s4[16]; float a1, a2, a30, a31; };

// s3 chunk swizzle: float4 chunk c (0..127) lives at float-offset
// S3OFF + 4*(c ^ ((c>>4)&7)). Involution, bijective, 16B-aligned. Makes the
// 16*(t&31)-pattern b128 reads 4-way instead of 16-way conflicted.
__device__ __forceinline__ int s3off(int c) {
  return S3OFF + 4 * (c ^ ((c >> 4) & 7));
}

__device__ __forceinline__ void load_sig(SigRegs& A, const float* __restrict__ B,
                                         int i_idx, int t) {
  const float4* p4 = (const float4*)(B + S4OFF + 16 * t);
#pragma unroll
  for (int r = 0; r < 4; ++r) {
    const float4 v = p4[r];
    A.s4[4 * r] = v.x; A.s4[4 * r + 1] = v.y; A.s4[4 * r + 2] = v.z; A.s4[4 * r + 3] = v.w;
  }
  A.a1 = B[S1OFF + i_idx];
  A.a2 = B[S2OFF + (t >> 2)];
  const float2 a3i = *(const float2*)(B + S3OFF + 2 * t);
  A.a30 = a3i.x; A.a31 = a3i.y;
}

__device__ __forceinline__ void store_sig(const SigRegs& A, float* __restrict__ o,
                                          int i_idx, int t) {
  if ((t & 31) == 0) o[S1OFF + i_idx] = A.a1;
  if ((t & 3) == 0) o[S2OFF + (t >> 2)] = A.a2;
  *(float2*)(o + S3OFF + 2 * t) = make_float2(A.a30, A.a31);
  float4* o4 = (float4*)(o + S4OFF + 16 * t);
#pragma unroll
  for (int r = 0; r < 4; ++r)
    o4[r] = make_float4(A.s4[4 * r], A.s4[4 * r + 1], A.s4[4 * r + 2], A.s4[4 * r + 3]);
}

// Chen left-fold A <- A*B; B lower levels from LDS row R, B.s4 own-slice from
// registers q4. Math identical to the verified round-2 kernel:
//   c4 = a4 + b4 + a1(x)b3 + a2(x)b2 + a3(x)b1
//   c3 = a3 + b3 + a1(x)b2 + a2(x)b1 ; c2 = a2 + b2 + a1(x)b1 ; c1 = a1 + b1
__device__ __forceinline__ void fold_lds(SigRegs& A, const float* __restrict__ R,
                                         const float4* __restrict__ q4,
                                         int i_idx, int j_idx, int k0, int t) {
  const float4 b1lo = *(const float4*)(R + S1OFF);
  const float4 b1hi = *(const float4*)(R + S1OFF + 4);
  const float b1i = R[S1OFF + i_idx];
  const float b1j = R[S1OFF + j_idx];
  const float2 b1k = *(const float2*)(R + S1OFF + k0);
  const float b2own = R[S2OFF + (t >> 2)];
  const float2 b2p = *(const float2*)(R + S2OFF + ((2 * t) & 63));
  const float2 b3p = *(const float2*)(R + s3off(t >> 1) + 2 * (t & 1));
  const float4* q2 = (const float4*)(R + S2OFF + 16 * (t & 3));
#pragma unroll
  for (int r = 0; r < 4; ++r) {
    const float4 v2 = q2[r];
    const float4 v3 = *(const float4*)(R + s3off(4 * (t & 31) + r));
    const float4 v4 = q4[r];
    const float a3v = (r < 2) ? A.a30 : A.a31;   // e<8 -> a30
    const float4 bb = (r & 1) ? b1hi : b1lo;     // b1v[(4r+c)&7]
    A.s4[4 * r + 0] += v4.x + A.a1 * v3.x + A.a2 * v2.x + a3v * bb.x;
    A.s4[4 * r + 1] += v4.y + A.a1 * v3.y + A.a2 * v2.y + a3v * bb.y;
    A.s4[4 * r + 2] += v4.z + A.a1 * v3.z + A.a2 * v2.z + a3v * bb.z;
    A.s4[4 * r + 3] += v4.w + A.a1 * v3.w + A.a2 * v2.w + a3v * bb.w;
  }
  A.a30 += b3p.x + A.a1 * b2p.x + A.a2 * b1k.x;
  A.a31 += b3p.y + A.a1 * b2p.y + A.a2 * b1k.y;
  A.a2 += b2own + A.a1 * b1j;
  A.a1 += b1i;
}

__device__ __forceinline__ void loadq4(float4* dst, const float* __restrict__ gbase,
                                       int m, int t) {
  const float4* g = (const float4*)(gbase + (long)m * SIGLEN + S4OFF + 16 * t);
#pragma unroll
  for (int r = 0; r < 4; ++r) dst[r] = g[r];
}

// Fold sigs gbase[0..NG-1] -> outp. NG = 8: stage rows 0..7 (row 0 unused),
// then 7 folds (sigs 1..7) with a 2-deep q4 double-buffer.
__device__ __forceinline__ void fold8(const float* __restrict__ gbase,
                                      float* __restrict__ outp,
                                      float* __restrict__ lsig,
                                      int i_idx, int j_idx, int k0, int t) {
  // Stage lower levels (146 float4 chunks x NG sigs = 1168) into LDS.
  // Static 5-slot batch (issue all loads, then all LDS writes); s3 swizzled.
  float4 vals[5];
#pragma unroll
  for (int s = 0; s < 5; ++s) {
    const int v = t + 256 * s;
    const int vc = (v < NG * 146) ? v : (NG * 146 - 1);
    const int sig = vc / 146;
    const int r = vc - sig * 146;
    vals[s] = *(const float4*)(gbase + (long)sig * SIGLEN + 4 * r);
  }

  SigRegs A;
  load_sig(A, gbase, i_idx, t);  // A = sig 0
  float4 qA[4], qB[4];
  loadq4(qA, gbase, 1, t);
  loadq4(qB, gbase, 2, t);

#pragma unroll
  for (int s = 0; s < 5; ++s) {
    const int v = t + 256 * s;
    if (v < NG * 146) {
      const int sig = v / 146;
      const int r = v - sig * 146;
      const int off = (r < 18) ? 4 * r : s3off(r - 18);
      *(float4*)(lsig + sig * LROW + off) = vals[s];
    }
  }
  __syncthreads();  // LDS staging complete

  // Folds 1..7: runtime loop, 2-wide software pipeline, named double-buffer.
#pragma unroll 1
  for (int m = 1; m + 2 < NG; m += 2) {  // m = 1, 3, 5 (6 folds)
    fold_lds(A, lsig + m * LROW, qA, i_idx, j_idx, k0, t);
    loadq4(qA, gbase, m + 2, t);
    fold_lds(A, lsig + (m + 1) * LROW, qB, i_idx, j_idx, k0, t);
    if (m + 3 < NG) loadq4(qB, gbase, m + 3, t);
  }
  fold_lds(A, lsig + (NG - 1) * LROW, qA, i_idx, j_idx, k0, t);  // fold 7
  store_sig(A, outp, i_idx, t);
}

// ------------------------- kernel 1: chunk signatures -------------------------
__global__ __launch_bounds__(256, 1) void sig_chunk(const float* __restrict__ path,
                                                    float* __restrict__ partials,
                                                    int nInc) {
  __shared__ float4 pl[(MAXLEN + 1) * 2];
  __shared__ float4 dv[MAXLEN * 2];
  const int t = threadIdx.x;
  const int c = blockIdx.x;
  const int i_idx = t >> 5;
  const int j_idx = (t >> 2) & 7;
  const int k0 = 2 * (t & 3);

  const long start = ((long)c * nInc) / NCHUNK;
  const long end = ((long)(c + 1) * nInc) / NCHUNK;
  const int len = (int)(end - start);

  const float4* gp = (const float4*)(path + start * 8);
  for (int idx = t; idx < (len + 1) * 2; idx += 256) pl[idx] = gp[idx];
  __syncthreads();
  for (int idx = t; idx < len * 2; idx += 256) {
    float4 a = pl[idx + 2], b = pl[idx];
    dv[idx] = make_float4(a.x - b.x, a.y - b.y, a.z - b.z, a.w - b.w);
  }
  __syncthreads();
  const float* dvf = (const float*)dv;

  SigRegs A;
#pragma unroll
  for (int e = 0; e < 16; ++e) A.s4[e] = 0.f;
  A.a1 = 0.f; A.a2 = 0.f; A.a30 = 0.f; A.a31 = 0.f;

  for (int it = 0; it < len; ++it) {
    const float4 d0 = dv[it * 2], d1 = dv[it * 2 + 1];
    const float dxl[8] = {d0.x, d0.y, d0.z, d0.w, d1.x, d1.y, d1.z, d1.w};
    const float dxi = dvf[it * 8 + i_idx];
    const float dxj = dvf[it * 8 + j_idx];
    const float2 dkk = *(const float2*)(dvf + it * 8 + k0);

    const float inner = 0.5f * A.a2 + dxj * ((1.f / 6.f) * A.a1 + (1.f / 24.f) * dxi);
    const float c0 = A.a30 + dkk.x * inner;
    const float c1 = A.a31 + dkk.y * inner;
#pragma unroll
    for (int l = 0; l < 8; ++l) A.s4[l] += c0 * dxl[l];
#pragma unroll
    for (int l = 0; l < 8; ++l) A.s4[8 + l] += c1 * dxl[l];
    const float common3 = A.a2 + dxj * (0.5f * A.a1 + (1.f / 6.f) * dxi);
    A.a30 += common3 * dkk.x;
    A.a31 += common3 * dkk.y;
    A.a2 += dxj * (A.a1 + 0.5f * dxi);
    A.a1 += dxi;
  }

  store_sig(A, partials + (long)c * SIGLEN, i_idx, t);
}

// ------------------- kernel 2: fold 8 chunk sigs per block -------------------
__global__ __launch_bounds__(256, 1) void sig_fold8(const float* __restrict__ in,
                                                    float* __restrict__ outp) {
  __shared__ float lsig[NG * LROW];  // 18944 B
  const int t = threadIdx.x;
  const int b = blockIdx.x;
  const int i_idx = t >> 5;
  const int j_idx = (t >> 2) & 7;
  const int k0 = 2 * (t & 3);
  fold8(in + (long)(NG * b) * SIGLEN, outp + (long)b * SIGLEN, lsig,
        i_idx, j_idx, k0, t);
}

// ---------------------- kernel 3: final fold of 8 sigs ----------------------
__global__ __launch_bounds__(256, 1) void sig_fold_final(const float* __restrict__ in,
                                                         float* __restrict__ outp) {
  __shared__ float lsig[NG * LROW];
  const int t = threadIdx.x;
  const int i_idx = t >> 5;
  const int j_idx = (t >> 2) & 7;
  const int k0 = 2 * (t & 3);
  fold8(in, outp, lsig, i_idx, j_idx, k0, t);
}

extern "C" void kernel_launch(void* const* d_in, const int* in_sizes, int n_in,
                              void* d_out, int out_size, void* d_ws, size_t ws_size,
                              hipStream_t stream) {
  const float* path = (const float*)d_in[0];
  float* out = (float*)d_out;
  const int L = in_sizes[0] / 8;
  const int nInc = L - 1;

  float* partials = (float*)d_ws;                    // NCHUNK * SIGLEN floats
  float* g2 = partials + (long)NCHUNK * SIGLEN;      // NG * SIGLEN floats

  sig_chunk<<<NCHUNK, 256, 0, stream>>>(path, partials, nInc);
  sig_fold8<<<NG, 256, 0, stream>>>(partials, g2);
  sig_fold_final<<<1, 256, 0, stream>>>(g2, out);
}